// Round 8
// baseline (166.073 us; speedup 1.0000x reference)
//
#include <hip/hip_runtime.h>
#include <hip/hip_bf16.h>
#include <stdint.h>

#define NB 32
#define NC 512
#define NP 576
#define NN 4096
#define APANEL8 294912u  // NP*NC bytes (fp8)
#define ATILE8 18432u    // NP*32 bytes per k-tile

typedef __attribute__((ext_vector_type(4))) float floatx4;

#define GLOAD_F32(dst, voff, sbase) \
  asm volatile("global_load_dword %0, %1, %2" : "=v"(dst) : "v"(voff), "s"(sbase))
#define GLOAD_B64(dst, voff, sbase) \
  asm volatile("global_load_dwordx2 %0, %1, %2" : "=v"(dst) : "v"(voff), "s"(sbase))
#define WAIT_VMCNT(N) asm volatile("s_waitcnt vmcnt(" #N ")" ::: "memory")
#define WAIT_LGKM0    asm volatile("s_waitcnt lgkmcnt(0)" ::: "memory")
#define SCHEDBAR() __builtin_amdgcn_sched_barrier(0)

// ---------------- K1: inverse L2 norms over channel dim (patch only) ----------------
__global__ void norms_kernel(const float* __restrict__ in, float* __restrict__ invn,
                             int nsp, int total) {
  int idx = blockIdx.x * 256 + threadIdx.x;
  if (idx >= total) return;
  int b = idx / nsp, sp = idx - b * nsp;
  const float* p = in + (size_t)b * NC * nsp + sp;
  float s = 0.f;
#pragma unroll 8
  for (int c = 0; c < NC; ++c) { float v = p[(size_t)c * nsp]; s = fmaf(v, v, s); }
  invn[idx] = 1.0f / fmaxf(sqrtf(s), 1e-12f);
}

// ---------------- K2: patch [C][P] -> fp8 fragment-tiled A2, scale ----------------
__global__ void transpose_kernel(const float* __restrict__ in, const float* __restrict__ invn,
                                 uint8_t* __restrict__ out, int nsp) {
  __shared__ float tile[64][65];
  int b = blockIdx.z, c0 = blockIdx.y * 64, p0 = blockIdx.x * 64;
  int tx = threadIdx.x & 63, ty = threadIdx.x >> 6;
  const float* src = in + ((size_t)b * NC + c0) * nsp + p0;
#pragma unroll
  for (int r = ty; r < 64; r += 4) tile[r][tx] = src[(size_t)r * nsp + tx];
  __syncthreads();
  int p = p0 + tx;
  float iv = invn[b * nsp + p];
  char* dst = (char*)out + (size_t)b * APANEL8
            + (uint32_t)(p >> 4) * 512u + (uint32_t)(p & 15) * 8u;
#pragma unroll
  for (int q = ty; q < 8; q += 4) {
    int c_local = q * 8, c_global = c0 + c_local;
    float f[8];
#pragma unroll
    for (int e = 0; e < 8; ++e) f[e] = tile[c_local + e][tx] * iv;
    int lo = 0, hi = 0;
    lo = __builtin_amdgcn_cvt_pk_fp8_f32(f[0], f[1], lo, false);
    lo = __builtin_amdgcn_cvt_pk_fp8_f32(f[2], f[3], lo, true);
    hi = __builtin_amdgcn_cvt_pk_fp8_f32(f[4], f[5], hi, false);
    hi = __builtin_amdgcn_cvt_pk_fp8_f32(f[6], f[7], hi, true);
    union { int i2[2]; long l; } u; u.i2[0] = lo; u.i2[1] = hi;
    uint32_t kt = (uint32_t)c_global >> 5, gg = ((uint32_t)c_global >> 3) & 3u;
    *(long*)(dst + kt * ATILE8 + gg * 128u) = u.l;
  }
}

// ---------------- K3: fused GEMM + softmax-reduction ----------------
// ONE independent wave per (b, jc): no barriers, no inter-wave coupling.
// Phase 1: stage own 64-j x-slice (coalesced), pack fp8 in-register, exchange
//   via tiny pitch-36 LDS (same-wave lgkm fences) into Bf[16][4] VGPRs + sumsq.
// Phase 2: 12 M-chunks x 16 k-steps; A-frags contiguous from A2, depth-2
//   ping-pong, vmcnt(3); per-chunk exp/reduce epilogue.
__global__ __launch_bounds__(64, 2)
void affinity_kernel(const uint8_t* __restrict__ A2,
                     const float* __restrict__ x,
                     float* __restrict__ partials) {
  const int bid = blockIdx.x;
  const int T = (bid & 7) * 256 + (bid >> 3);   // bijective XCD swizzle (2048 = 8*256)
  const int b = T >> 6, jc = T & 63;
  const int lane = threadIdx.x;
  const int g = lane >> 4, l15 = lane & 15;

  __shared__ __align__(8) char ex[64 * 36];
  __shared__ float sqx[64];

  const uint64_t sA = (uint64_t)(uintptr_t)A2;
  const uint64_t sX = (uint64_t)(uintptr_t)x;

  const uint32_t vGbase = (uint32_t)(b * NC) * (uint32_t)(NN * 4)
                        + (uint32_t)(jc * 64 + lane) * 4u;

  long Bf[16][4];
  float GR[32], GS[32];
  float sq = 0.f;

  auto proc = [&](float (&G)[32], int KT) {
#pragma unroll
    for (int r = 0; r < 32; ++r) sq = fmaf(G[r], G[r], sq);
#pragma unroll
    for (int gg = 0; gg < 4; ++gg) {
      int lo = 0, hi = 0;
      lo = __builtin_amdgcn_cvt_pk_fp8_f32(G[gg * 8 + 0], G[gg * 8 + 1], lo, false);
      lo = __builtin_amdgcn_cvt_pk_fp8_f32(G[gg * 8 + 2], G[gg * 8 + 3], lo, true);
      hi = __builtin_amdgcn_cvt_pk_fp8_f32(G[gg * 8 + 4], G[gg * 8 + 5], hi, false);
      hi = __builtin_amdgcn_cvt_pk_fp8_f32(G[gg * 8 + 6], G[gg * 8 + 7], hi, true);
      *(int*)(ex + lane * 36 + gg * 8) = lo;
      *(int*)(ex + lane * 36 + gg * 8 + 4) = hi;
    }
    WAIT_LGKM0; SCHEDBAR();             // writes visible to all lanes
#pragma unroll
    for (int q = 0; q < 4; ++q) {
      union { int i[2]; long l; } u;
      u.i[0] = *(const int*)(ex + (q * 16 + l15) * 36 + g * 8);
      u.i[1] = *(const int*)(ex + (q * 16 + l15) * 36 + g * 8 + 4);
      Bf[KT][q] = u.l;
    }
    WAIT_LGKM0; SCHEDBAR();             // reads done before next kt's writes
  };

  // ---- phase 1: stage + pack (ping-pong 32-row batches, counted vmcnt) ----
#pragma unroll
  for (int r = 0; r < 32; ++r) GLOAD_F32(GR[r], vGbase + (uint32_t)r * 16384u, sX);
#pragma unroll
  for (int kt = 0; kt < 16; ++kt) {
    if (kt < 15) {
      uint32_t vb = vGbase + (uint32_t)(kt + 1) * 524288u;
      if (kt & 1) {
#pragma unroll
        for (int r = 0; r < 32; ++r) GLOAD_F32(GR[r], vb + (uint32_t)r * 16384u, sX);
      } else {
#pragma unroll
        for (int r = 0; r < 32; ++r) GLOAD_F32(GS[r], vb + (uint32_t)r * 16384u, sX);
      }
      WAIT_VMCNT(32);
    } else {
      WAIT_VMCNT(0);
    }
    SCHEDBAR();
    if (kt & 1) proc(GS, kt); else proc(GR, kt);
  }

  // ---- sumsq exchange + A prologue ----
  sqx[lane] = sq;
  WAIT_LGKM0; SCHEDBAR();
  uint32_t vA_c = (uint32_t)b * APANEL8 + (uint32_t)lane * 8u;
  long afA[3], afB[3];
#pragma unroll
  for (int mi = 0; mi < 3; ++mi) GLOAD_B64(afA[mi], vA_c + (uint32_t)mi * 512u, sA);
#pragma unroll
  for (int mi = 0; mi < 3; ++mi) GLOAD_B64(afB[mi], vA_c + (uint32_t)mi * 512u + ATILE8, sA);

  float iv[4], cxj[4];
#pragma unroll
  for (int q = 0; q < 4; ++q) {
    iv[q] = rsqrtf(fmaxf(sqx[q * 16 + l15], 1e-24f)) * 1.44269504088896340736f;
    cxj[q] = (float)(q * 16 + l15) + 0.5f;
  }

  // ---- phase 2: 12 chunks x 16 k-steps ----
#pragma unroll 1
  for (int c = 0; c < 12; ++c) {
    floatx4 acc[3][4];
#pragma unroll
    for (int mi = 0; mi < 3; ++mi)
#pragma unroll
      for (int q = 0; q < 4; ++q) acc[mi][q] = (floatx4){0.f, 0.f, 0.f, 0.f};

#pragma unroll
    for (int kt = 0; kt < 16; ++kt) {
      WAIT_VMCNT(3); SCHEDBAR();
      uint32_t nb = vA_c + (kt >= 14 ? 1536u : 0u)
                  + (uint32_t)((kt + 2) & 15) * ATILE8;
      if (kt & 1) {
#pragma unroll
        for (int q = 0; q < 4; ++q)
#pragma unroll
          for (int mi = 0; mi < 3; ++mi)
            acc[mi][q] = __builtin_amdgcn_mfma_f32_16x16x32_fp8_fp8(afB[mi], Bf[kt][q], acc[mi][q], 0, 0, 0);
#pragma unroll
        for (int mi = 0; mi < 3; ++mi) GLOAD_B64(afB[mi], nb + (uint32_t)mi * 512u, sA);
      } else {
#pragma unroll
        for (int q = 0; q < 4; ++q)
#pragma unroll
          for (int mi = 0; mi < 3; ++mi)
            acc[mi][q] = __builtin_amdgcn_mfma_f32_16x16x32_fp8_fp8(afA[mi], Bf[kt][q], acc[mi][q], 0, 0, 0);
#pragma unroll
        for (int mi = 0; mi < 3; ++mi) GLOAD_B64(afA[mi], nb + (uint32_t)mi * 512u, sA);
      }
    }
    vA_c += 1536u;

    // ---- epilogue for chunk c (cy = jc + 0.5 handled in finalize) ----
#pragma unroll
    for (int mi = 0; mi < 3; ++mi) {
      float s[4] = {0.f, 0.f, 0.f, 0.f}, sx[4] = {0.f, 0.f, 0.f, 0.f};
#pragma unroll
      for (int q = 0; q < 4; ++q)
#pragma unroll
        for (int r = 0; r < 4; ++r) {
          float p = exp2f(acc[mi][q][r] * iv[q]);
          s[r] += p;
          sx[r] = fmaf(p, cxj[q], sx[r]);
        }
#pragma unroll
      for (int r = 0; r < 4; ++r) {
#pragma unroll
        for (int m = 1; m < 16; m <<= 1) {
          s[r] += __shfl_xor(s[r], m);
          sx[r] += __shfl_xor(sx[r], m);
        }
      }
      if (l15 == 0) {
#pragma unroll
        for (int r = 0; r < 4; ++r) {
          int row = c * 48 + mi * 16 + g * 4 + r;
          float* o = partials + ((size_t)(b * NP + row) * 64 + jc) * 2;
          o[0] = s[r];
          o[1] = sx[r];
        }
      }
    }
  }
  WAIT_VMCNT(0);   // drain tail prefetches before endpgm
}

// ---------------- K4: finalize ----------------
__global__ void finalize_kernel(const float* __restrict__ partials, float* __restrict__ out) {
  int b = blockIdx.x;
  int t = threadIdx.x;
  float sxt = 0.f, syt = 0.f;
  for (int i = t; i < NP; i += 256) {
    const float* p = partials + ((size_t)(b * NP + i) * 64) * 2;
    float s = 0.f, sx = 0.f, sy = 0.f;
#pragma unroll
    for (int jc2 = 0; jc2 < 64; ++jc2) {
      float ss = p[jc2 * 2];
      s += ss;
      sx += p[jc2 * 2 + 1];
      sy = fmaf(ss, (float)jc2 + 0.5f, sy);
    }
    sxt += sx / s;
    syt += sy / s;
  }
  __shared__ float rs[256], rs2[256];
  rs[t] = sxt; rs2[t] = syt;
  __syncthreads();
  for (int o = 128; o > 0; o >>= 1) {
    if (t < o) { rs[t] += rs[t + o]; rs2[t] += rs2[t + o]; }
    __syncthreads();
  }
  if (t == 0) {
    float cx = rs[0] / (float)NP, cy = rs2[0] / (float)NP;
    float l = fmaxf(cx - 12.f, 0.f);
    float tp = fmaxf(cy - 12.f, 0.f);
    out[b * 4 + 0] = l;
    out[b * 4 + 1] = tp;
    out[b * 4 + 2] = fminf(l + 24.f, 64.f);
    out[b * 4 + 3] = fminf(tp + 24.f, 64.f);
  }
}

extern "C" void kernel_launch(void* const* d_in, const int* in_sizes, int n_in,
                              void* d_out, int out_size, void* d_ws, size_t ws_size,
                              hipStream_t stream) {
  const float* patch_x = (const float*)d_in[0];
  const float* x = (const float*)d_in[1];
  float* out = (float*)d_out;
  char* ws = (char*)d_ws;

  float* inv_src = (float*)(ws + 0);                  //    73,728 B
  uint8_t* A2 = (uint8_t*)(ws + 73728);               //  9,437,184 B (fp8)
  float* partials = (float*)(ws + 9510912);           //  9,437,184 B

  norms_kernel<<<dim3((NB * NP + 255) / 256), 256, 0, stream>>>(patch_x, inv_src, NP, NB * NP);
  transpose_kernel<<<dim3(NP / 64, NC / 64, NB), 256, 0, stream>>>(patch_x, inv_src, A2, NP);
  affinity_kernel<<<dim3(NB * 64), 64, 0, stream>>>(A2, x, partials);
  finalize_kernel<<<NB, 256, 0, stream>>>(partials, out);
}